// Round 6
// baseline (430.014 us; speedup 1.0000x reference)
//
#include <hip/hip_runtime.h>
#include <hip/hip_fp16.h>
#include <hip/hip_fp8.h>

#define NNODES 4096
#define LWALK 16
#define ODIM 8

#define FP8_SCALE 256.0f
#define FP8_INV   0.00390625f          // 1/256
#define FP8_INV2  1.52587890625e-05f   // 1/65536

typedef unsigned int uint4n __attribute__((ext_vector_type(4)));
typedef float float2n __attribute__((ext_vector_type(2)));

// ---------- fp8 helpers ----------
__device__ __forceinline__ void dec8f(unsigned int lo, unsigned int hi, float* f) {
#if __has_builtin(__builtin_amdgcn_cvt_pk_f32_fp8)
    float2n p;
    p = __builtin_amdgcn_cvt_pk_f32_fp8((int)lo, false); f[0] = p.x; f[1] = p.y;
    p = __builtin_amdgcn_cvt_pk_f32_fp8((int)lo, true);  f[2] = p.x; f[3] = p.y;
    p = __builtin_amdgcn_cvt_pk_f32_fp8((int)hi, false); f[4] = p.x; f[5] = p.y;
    p = __builtin_amdgcn_cvt_pk_f32_fp8((int)hi, true);  f[6] = p.x; f[7] = p.y;
#else
    unsigned int w[2] = {lo, hi};
    const unsigned char* b = (const unsigned char*)w;
#pragma unroll
    for (int i = 0; i < 8; ++i) {
        __hip_fp8_e4m3 t; t.__x = b[i]; f[i] = (float)t;
    }
#endif
}

__device__ __forceinline__ void enc8f(const float* a, unsigned int* lo,
                                      unsigned int* hi) {
#if __has_builtin(__builtin_amdgcn_cvt_pk_fp8_f32)
    int l = 0, h = 0;
    l = __builtin_amdgcn_cvt_pk_fp8_f32(a[0], a[1], l, false);
    l = __builtin_amdgcn_cvt_pk_fp8_f32(a[2], a[3], l, true);
    h = __builtin_amdgcn_cvt_pk_fp8_f32(a[4], a[5], h, false);
    h = __builtin_amdgcn_cvt_pk_fp8_f32(a[6], a[7], h, true);
    *lo = (unsigned int)l; *hi = (unsigned int)h;
#else
    unsigned char b[8];
#pragma unroll
    for (int i = 0; i < 8; ++i)
        b[i] = __hip_cvt_float_to_fp8(a[i], __HIP_SATFINITE, __HIP_E4M3);
    unsigned int w[2];
    __builtin_memcpy(w, b, 8);
    *lo = w[0]; *hi = w[1];
#endif
}

__device__ __forceinline__ void dec16f(uint4n w, float* f) {
    dec8f(w.x, w.y, f);
    dec8f(w.z, w.w, f + 8);
}

// ---------- edge-index dtype detection ----------
__global__ void detect_fmt_k(const void* ei, int E, int* flag) {
    if (blockIdx.x == 0 && threadIdx.x == 0) {
        const long long* p = (const long long*)ei;
        int ok = 1;
        for (int i = 0; i < 64; ++i) {
            long long v = p[i];
            if (v < 0 || v >= NNODES) { ok = 0; break; }
        }
        *flag = ok;
    }
}

__device__ __forceinline__ int load_idx(const void* p, int i, int fmt) {
    if (fmt) return (int)((const long long*)p)[i];
    return ((const int*)p)[i];
}

__global__ void build_deg_cnt_k(const void* ei, int E, int* deg, int* cnt,
                                const int* fmt) {
    int e = blockIdx.x * blockDim.x + threadIdx.x;
    if (e >= E) return;
    int f = *fmt;
    int r = load_idx(ei, e, f);
    int c = load_idx(ei, E + e, f);
    atomicAdd(&deg[r], 1);    // out-degree
    atomicAdd(&cnt[c], 1);    // in-degree
}

// ---------- exclusive scan over padded (multiple-of-4) counts ----------
__global__ void scan_k(const int* __restrict__ cnt, int* __restrict__ rowptr,
                       int* __restrict__ cursor) {
    __shared__ int sm[1024];
    int tid = threadIdx.x;
    int v0 = (cnt[4 * tid + 0] + 3) & ~3;
    int v1 = (cnt[4 * tid + 1] + 3) & ~3;
    int v2 = (cnt[4 * tid + 2] + 3) & ~3;
    int v3 = (cnt[4 * tid + 3] + 3) & ~3;
    int tsum = v0 + v1 + v2 + v3;
    sm[tid] = tsum;
    __syncthreads();
    int val = tsum;
    for (int off = 1; off < 1024; off <<= 1) {
        int t = (tid >= off) ? sm[tid - off] : 0;
        __syncthreads();
        val += t;
        sm[tid] = val;
        __syncthreads();
    }
    int excl = val - tsum;
    int p0 = excl, p1 = excl + v0, p2 = p1 + v1, p3 = p2 + v2;
    rowptr[4 * tid + 0] = p0; rowptr[4 * tid + 1] = p1;
    rowptr[4 * tid + 2] = p2; rowptr[4 * tid + 3] = p3;
    cursor[4 * tid + 0] = p0; cursor[4 * tid + 1] = p1;
    cursor[4 * tid + 2] = p2; cursor[4 * tid + 3] = p3;
    if (tid == 1023) rowptr[4096] = val;
}

// ---------- fill CSRs ----------
// in-CSR (by destination): packed 4B edge = fp16(1/deg(src))<<16 | src
// out-CSR (by source): 4B dest index; true end tracked by ocursor (no pads).
__global__ void fill_pad_k(const void* ei, int E, const int* __restrict__ deg,
                           int* cursor, int* ocursor,
                           unsigned int* __restrict__ ep4,
                           unsigned int* __restrict__ oidx, const int* fmt) {
    int e = blockIdx.x * blockDim.x + threadIdx.x;
    if (e < E) {
        int f = *fmt;
        int r = load_idx(ei, e, f);
        int c = load_idx(ei, E + e, f);
        int d = deg[r];
        float v = 1.0f / (float)(d < 1 ? 1 : d);
        int pos = atomicAdd(&cursor[c], 1);
        unsigned hv = (unsigned)__half_as_ushort(__float2half(v));
        ep4[pos] = (hv << 16) | (unsigned)r;
        int opos = atomicAdd(&ocursor[r], 1);
        oidx[opos] = (unsigned)c;
    }
}

__global__ void pad_fill_k(const int* __restrict__ rowptr,
                           const int* __restrict__ cursor,
                           unsigned int* __restrict__ ep4) {
    int c = blockIdx.x * blockDim.x + threadIdx.x;
    if (c >= NNODES) return;
    for (int p = cursor[c]; p < rowptr[c + 1]; ++p)
        ep4[p] = 0u;   // src=0, v(fp16)=0 -> contributes nothing
}

// ---------- fused chain: X2 build (out-walk) + X3..X8 SpMM per 8-col slab ----
// LDS layout (the round-6 fix): 2 buffers x 4 "column-pair" arrays of
// [4096 rows] x uint (2 fp16 cols packed). Row stride = 4B -> a wave's 64
// random-row gathers alias banks only 2-way (free, m136), vs 4-8-way before.
// fp16 storage kills the per-edge fp8 decode chain: per edge = 1 addr +
// 4 ds_read_b32 (imm offsets) + 2-inst w-splat + 4 v_pk_fma_f16.
__global__ __launch_bounds__(512, 1) void chain_k(
    const int* __restrict__ rowptr, const unsigned int* __restrict__ ep4,
    const int* __restrict__ orowptr, const int* __restrict__ ocursor,
    const unsigned int* __restrict__ oidx, const int* __restrict__ deg,
    float* __restrict__ rw,
    unsigned char* __restrict__ M4, unsigned char* __restrict__ M5,
    unsigned char* __restrict__ M7, unsigned char* __restrict__ M8) {
    __shared__ unsigned int chainbuf[2 * 4 * NNODES];   // 128 KB
    const int t = threadIdx.x;
    const int bid = blockIdx.x;
    const int slab = (bid & 7) * 64 + (bid >> 3);   // sibling slabs per XCD
    const int S0 = slab * 8;

    // ---- Phase 1: X2 columns S0..S0+7 via OUT-edge two-level walk ----
    // X2[s,gc] = sum_{gc->m->s} (1/deg gc)(1/deg m)
    float* col32 = (float*)&chainbuf[4 * NNODES];   // 16 KB scratch in buf1
    __half* hb = (__half*)chainbuf;
    const int g = t >> 4;                 // edge1 slot [0,32)
    const int l = t & 15;                 // edge2 lane [0,16)
    for (int cl = 0; cl < 8; ++cl) {
        const int gc = S0 + cl;
        for (int i = t; i < NNODES; i += 512) col32[i] = 0.f;
        __syncthreads();
        const int dg = deg[gc];
        const float vg = 1.f / (float)(dg < 1 ? 1 : dg);
        const int ob = orowptr[gc], oe = ocursor[gc];
        for (int p1 = ob + g; p1 < oe; p1 += 32) {
            int m = (int)oidx[p1];
            if (m == gc && l == 0)
                atomicAdd(&rw[gc * LWALK + 0], vg);   // k=1 diag (self-loops)
            int dm = deg[m];
            float vm = vg / (float)(dm < 1 ? 1 : dm);
            int mb = orowptr[m], me = ocursor[m];
            for (int p2 = mb + l; p2 < me; p2 += 16)
                atomicAdd(&col32[oidx[p2]], vm);
        }
        __syncthreads();
        if (t == 0) rw[gc * LWALK + 1] = col32[gc];   // k=2 diag (fp32)
        // write column cl into buf0 fp16 pair layout:
        // half index = ((cl>>1)*4096 + i)*2 + (cl&1)
        for (int i = t; i < NNODES; i += 512)
            hb[(((cl >> 1) * NNODES + i) << 1) + (cl & 1)] =
                __float2half(col32[i] * FP8_SCALE);
        __syncthreads();
    }

    // ---- Phase 2: X3..X8 LDS->LDS SpMM; diags k3..k8; store X4,X5,X7,X8 ----
    int rpb[8], rpe[8];
#pragma unroll
    for (int j = 0; j < 8; ++j) {
        rpb[j] = rowptr[t + 512 * j];
        rpe[j] = rowptr[t + 512 * j + 1];
    }
#pragma unroll 1
    for (int k = 3; k <= 8; ++k) {
        const int si = (k & 1) ^ 1;   // k=3: src buf0 = X2
        const int di = k & 1;
        const unsigned sidx = (unsigned)si * (4 * NNODES);
        const unsigned didx = (unsigned)di * (4 * NNODES);
        __syncthreads();   // prior step's dst (this step's src) complete
#pragma unroll 1
        for (int j = 0; j < 8; ++j) {
            const int c = t + 512 * j;
            __half2 acc[4];
#pragma unroll
            for (int u = 0; u < 4; ++u)
                acc[u] = __half2half2(__ushort_as_half((unsigned short)0));
            for (int e = rpb[j]; e < rpe[j]; e += 4) {
                uint4n ew = *(const uint4n*)(ep4 + e);
#pragma unroll
                for (int q = 0; q < 4; ++q) {
                    unsigned w = (q == 0) ? ew.x : (q == 1) ? ew.y
                               : (q == 2) ? ew.z : ew.w;
                    unsigned r_ = w & 0xFFFFu;
                    unsigned ws_ = (w & 0xFFFF0000u) | (w >> 16);
                    __half2 w2 = *(__half2*)&ws_;
                    unsigned b_ = sidx + r_;
                    unsigned x0 = chainbuf[b_];
                    unsigned x1 = chainbuf[b_ + NNODES];
                    unsigned x2 = chainbuf[b_ + 2 * NNODES];
                    unsigned x3 = chainbuf[b_ + 3 * NNODES];
                    acc[0] = __hfma2(*(__half2*)&x0, w2, acc[0]);
                    acc[1] = __hfma2(*(__half2*)&x1, w2, acc[1]);
                    acc[2] = __hfma2(*(__half2*)&x2, w2, acc[2]);
                    acc[3] = __hfma2(*(__half2*)&x3, w2, acc[3]);
                }
            }
            if ((unsigned)(c - S0) < 8u) {
                const int u = c - S0;
                float d = 0.f;
#pragma unroll
                for (int uu = 0; uu < 4; ++uu)
                    if ((u >> 1) == uu)
                        d = (u & 1) ? __high2float(acc[uu])
                                    : __low2float(acc[uu]);
                rw[c * LWALK + (k - 1)] = d * FP8_INV;   // diag k
            }
            // write dst rows (stride-1 in rows -> conflict-free)
#pragma unroll
            for (int u = 0; u < 4; ++u)
                chainbuf[didx + u * NNODES + c] = *(unsigned*)&acc[u];
            // HBM stage for the pair stage (scaled fp8), straight from regs
            if (k == 4 || k == 5 || k == 7 || k == 8) {
                unsigned char* M = (k == 4) ? M4 : (k == 5) ? M5
                                 : (k == 7) ? M7 : M8;
                float fa[8];
#pragma unroll
                for (int u = 0; u < 4; ++u) {
                    fa[2 * u] = __low2float(acc[u]);
                    fa[2 * u + 1] = __high2float(acc[u]);
                }
                unsigned int lo, hi;
                enc8f(fa, &lo, &hi);
                *(uint2*)(M + (size_t)c * NNODES + S0) = make_uint2(lo, hi);
            }
        }
    }
}

// ---------- pairdiags k9..k16: 4 groups x 1024 blocks, one launch ----------
// grp g computes colO = diag(PA*PB1), colE = diag(PA*PB2):
//   g0: (X5,X4,X5)->k9,k10   g1: (X7,X4,X7)->k11,k14
//   g2: (X8,X4,X8)->k12,k16  g3: (X8,X5,X7)->k13,k15
__global__ __launch_bounds__(256) void pairall_k(
    const unsigned char* __restrict__ M4, const unsigned char* __restrict__ M5,
    const unsigned char* __restrict__ M7, const unsigned char* __restrict__ M8,
    float* __restrict__ rw) {
    __shared__ __half bt[64][66];
    __shared__ __half ct[64][66];
    const int bid = blockIdx.x;
    const int grp = bid >> 10;
    const int pb = bid & 1023;
    const unsigned char* PA;
    const unsigned char* PB1;
    const unsigned char* PB2;
    int colO, colE;
    if (grp == 0)      { PA = M5; PB1 = M4; PB2 = M5; colO = 8;  colE = 9;  }
    else if (grp == 1) { PA = M7; PB1 = M4; PB2 = M7; colO = 10; colE = 13; }
    else if (grp == 2) { PA = M8; PB1 = M4; PB2 = M8; colO = 11; colE = 15; }
    else               { PA = M8; PB1 = M5; PB2 = M7; colO = 12; colE = 14; }
    const int i0 = (pb & 63) * 64;
    const int Jbeg = (pb >> 6) * (NNODES / 16);
    const int Jend = Jbeg + (NNODES / 16);
    const int t = threadIdx.x;
    const int li = t >> 2;
    const int q = t & 3;
    const int c0 = q * 16;
    float accO = 0.f, accE = 0.f;
    for (int J = Jbeg; J < Jend; J += 64) {
        uint4n b16 = __builtin_nontemporal_load(
            (const uint4n*)(PB1 + (size_t)(J + li) * NNODES + i0 + c0));
        uint4n g16 = __builtin_nontemporal_load(
            (const uint4n*)(PB2 + (size_t)(J + li) * NNODES + i0 + c0));
        __syncthreads();
        float bf[16], gf[16];
        dec16f(b16, bf);
        dec16f(g16, gf);
#pragma unroll
        for (int s = 0; s < 16; ++s) {
            bt[c0 + s][li] = __float2half(bf[s]);  // fp8 values exact in fp16
            ct[c0 + s][li] = __float2half(gf[s]);
        }
        __syncthreads();
        uint4n a16 = __builtin_nontemporal_load(
            (const uint4n*)(PA + (size_t)(i0 + li) * NNODES + J + c0));
        float af[16];
        dec16f(a16, af);
#pragma unroll
        for (int s = 0; s < 16; ++s) {
            accO = fmaf(af[s], __half2float(bt[li][c0 + s]), accO);
            accE = fmaf(af[s], __half2float(ct[li][c0 + s]), accE);
        }
    }
    accO += __shfl_xor(accO, 1);
    accO += __shfl_xor(accO, 2);
    accE += __shfl_xor(accE, 1);
    accE += __shfl_xor(accE, 2);
    if (q == 0) {
        atomicAdd(&rw[(i0 + li) * LWALK + colO], accO * FP8_INV2);
        atomicAdd(&rw[(i0 + li) * LWALK + colE], accE * FP8_INV2);
    }
}

// ---------- final linear ----------
__global__ void linear_k(const float* __restrict__ rw, const float* __restrict__ W,
                         const float* __restrict__ b, float* __restrict__ out) {
    int i = blockIdx.x * blockDim.x + threadIdx.x;
    if (i >= NNODES * ODIM) return;
    int s = i >> 3, d = i & 7;
    float acc = b[d];
#pragma unroll
    for (int k = 0; k < LWALK; ++k)
        acc = fmaf(rw[s * LWALK + k], W[d * LWALK + k], acc);
    out[i] = acc;
}

extern "C" void kernel_launch(void* const* d_in, const int* in_sizes, int n_in,
                              void* d_out, int out_size, void* d_ws, size_t ws_size,
                              hipStream_t stream) {
    const void* ei = d_in[0];
    int E = in_sizes[0] / 2;
    const float* W = (const float*)d_in[2];
    const float* bias = (const float*)d_in[3];
    float* out = (float*)d_out;

    char* ws = (char*)d_ws;
    size_t off = 0;
    auto alloc = [&](size_t bytes) -> char* {
        char* p = ws + off;
        off = (off + bytes + 255) & ~(size_t)255;
        return p;
    };
    int* flag = (int*)alloc(4);
    int* deg = (int*)alloc(NNODES * 4);
    int* cnt = (int*)alloc(NNODES * 4);
    int* rowptr = (int*)alloc((NNODES + 1) * 4);
    int* cursor = (int*)alloc(NNODES * 4);
    int* orowptr = (int*)alloc((NNODES + 1) * 4);
    int* ocursor = (int*)alloc(NNODES * 4);
    unsigned int* ep4 = (unsigned int*)alloc(((size_t)E + 4 * NNODES) * 4);
    unsigned int* oidx = (unsigned int*)alloc(((size_t)E + 4 * NNODES) * 4);
    float* rw = (float*)alloc(NNODES * LWALK * 4);
    unsigned char* M4 = (unsigned char*)alloc((size_t)NNODES * NNODES);
    unsigned char* M5 = (unsigned char*)alloc((size_t)NNODES * NNODES);
    unsigned char* M7 = (unsigned char*)alloc((size_t)NNODES * NNODES);
    unsigned char* M8 = (unsigned char*)alloc((size_t)NNODES * NNODES);

    (void)hipMemsetAsync(deg, 0, NNODES * 4, stream);
    (void)hipMemsetAsync(cnt, 0, NNODES * 4, stream);
    (void)hipMemsetAsync(rw, 0, NNODES * LWALK * 4, stream);
    detect_fmt_k<<<1, 64, 0, stream>>>(ei, E, flag);
    build_deg_cnt_k<<<(E + 255) / 256, 256, 0, stream>>>(ei, E, deg, cnt, flag);
    scan_k<<<1, 1024, 0, stream>>>(cnt, rowptr, cursor);     // in-CSR
    scan_k<<<1, 1024, 0, stream>>>(deg, orowptr, ocursor);   // out-CSR
    fill_pad_k<<<(E + 255) / 256, 256, 0, stream>>>(ei, E, deg, cursor, ocursor,
                                                    ep4, oidx, flag);
    pad_fill_k<<<(NNODES + 255) / 256, 256, 0, stream>>>(rowptr, cursor, ep4);

    // Fused chain: X2 (out-walk) + X3..X8 in fp16 LDS; diags k1..k8;
    // X4,X5,X7,X8 -> HBM (scaled fp8) for the pair stage.
    chain_k<<<512, 512, 0, stream>>>(rowptr, ep4, orowptr, ocursor, oidx, deg,
                                     rw, M4, M5, M7, M8);

    // Pairdiags k9..k16.
    pairall_k<<<4096, 256, 0, stream>>>(M4, M5, M7, M8, rw);

    linear_k<<<(NNODES * ODIM + 255) / 256, 256, 0, stream>>>(rw, W, bias, out);
}

// Round 8
// 309.825 us; speedup vs baseline: 1.3879x; 1.3879x over previous
//
#include <hip/hip_runtime.h>
#include <hip/hip_fp16.h>
#include <hip/hip_fp8.h>

#define NNODES 4096
#define LWALK 16
#define ODIM 8

#define FP8_SCALE 256.0f
#define FP8_INV   0.00390625f          // 1/256
#define FP8_INV2  1.52587890625e-05f   // 1/65536

typedef unsigned int uint4n __attribute__((ext_vector_type(4)));
typedef float float2n __attribute__((ext_vector_type(2)));

// ---------- fp8 helpers ----------
__device__ __forceinline__ void dec8f(unsigned int lo, unsigned int hi, float* f) {
#if __has_builtin(__builtin_amdgcn_cvt_pk_f32_fp8)
    float2n p;
    p = __builtin_amdgcn_cvt_pk_f32_fp8((int)lo, false); f[0] = p.x; f[1] = p.y;
    p = __builtin_amdgcn_cvt_pk_f32_fp8((int)lo, true);  f[2] = p.x; f[3] = p.y;
    p = __builtin_amdgcn_cvt_pk_f32_fp8((int)hi, false); f[4] = p.x; f[5] = p.y;
    p = __builtin_amdgcn_cvt_pk_f32_fp8((int)hi, true);  f[6] = p.x; f[7] = p.y;
#else
    unsigned int w[2] = {lo, hi};
    const unsigned char* b = (const unsigned char*)w;
#pragma unroll
    for (int i = 0; i < 8; ++i) {
        __hip_fp8_e4m3 t; t.__x = b[i]; f[i] = (float)t;
    }
#endif
}

__device__ __forceinline__ void enc8f(const float* a, unsigned int* lo,
                                      unsigned int* hi) {
#if __has_builtin(__builtin_amdgcn_cvt_pk_fp8_f32)
    int l = 0, h = 0;
    l = __builtin_amdgcn_cvt_pk_fp8_f32(a[0], a[1], l, false);
    l = __builtin_amdgcn_cvt_pk_fp8_f32(a[2], a[3], l, true);
    h = __builtin_amdgcn_cvt_pk_fp8_f32(a[4], a[5], h, false);
    h = __builtin_amdgcn_cvt_pk_fp8_f32(a[6], a[7], h, true);
    *lo = (unsigned int)l; *hi = (unsigned int)h;
#else
    unsigned char b[8];
#pragma unroll
    for (int i = 0; i < 8; ++i)
        b[i] = __hip_cvt_float_to_fp8(a[i], __HIP_SATFINITE, __HIP_E4M3);
    unsigned int w[2];
    __builtin_memcpy(w, b, 8);
    *lo = w[0]; *hi = w[1];
#endif
}

__device__ __forceinline__ void dec16f(uint4n w, float* f) {
    dec8f(w.x, w.y, f);
    dec8f(w.z, w.w, f + 8);
}

__device__ __forceinline__ uint4n enc16f(const float* a) {
    uint4n o;
    unsigned int lo, hi;
    enc8f(a, &lo, &hi);     o.x = lo; o.y = hi;
    enc8f(a + 8, &lo, &hi); o.z = lo; o.w = hi;
    return o;
}

// ---------- edge-index dtype detection ----------
__global__ void detect_fmt_k(const void* ei, int E, int* flag) {
    if (blockIdx.x == 0 && threadIdx.x == 0) {
        const long long* p = (const long long*)ei;
        int ok = 1;
        for (int i = 0; i < 64; ++i) {
            long long v = p[i];
            if (v < 0 || v >= NNODES) { ok = 0; break; }
        }
        *flag = ok;
    }
}

__device__ __forceinline__ int load_idx(const void* p, int i, int fmt) {
    if (fmt) return (int)((const long long*)p)[i];
    return ((const int*)p)[i];
}

__global__ void build_deg_cnt_k(const void* ei, int E, int* deg, int* cnt,
                                const int* fmt) {
    int e = blockIdx.x * blockDim.x + threadIdx.x;
    if (e >= E) return;
    int f = *fmt;
    int r = load_idx(ei, e, f);
    int c = load_idx(ei, E + e, f);
    atomicAdd(&deg[r], 1);
    atomicAdd(&cnt[c], 1);
}

// ---------- exclusive scan over padded (multiple-of-4) counts ----------
__global__ void scan_k(const int* __restrict__ cnt, int* __restrict__ rowptr,
                       int* __restrict__ cursor) {
    __shared__ int sm[1024];
    int tid = threadIdx.x;
    int v0 = (cnt[4 * tid + 0] + 3) & ~3;
    int v1 = (cnt[4 * tid + 1] + 3) & ~3;
    int v2 = (cnt[4 * tid + 2] + 3) & ~3;
    int v3 = (cnt[4 * tid + 3] + 3) & ~3;
    int tsum = v0 + v1 + v2 + v3;
    sm[tid] = tsum;
    __syncthreads();
    int val = tsum;
    for (int off = 1; off < 1024; off <<= 1) {
        int t = (tid >= off) ? sm[tid - off] : 0;
        __syncthreads();
        val += t;
        sm[tid] = val;
        __syncthreads();
    }
    int excl = val - tsum;
    int p0 = excl, p1 = excl + v0, p2 = p1 + v1, p3 = p2 + v2;
    rowptr[4 * tid + 0] = p0; rowptr[4 * tid + 1] = p1;
    rowptr[4 * tid + 2] = p2; rowptr[4 * tid + 3] = p3;
    cursor[4 * tid + 0] = p0; cursor[4 * tid + 1] = p1;
    cursor[4 * tid + 2] = p2; cursor[4 * tid + 3] = p3;
    if (tid == 1023) rowptr[4096] = val;
}

// ---------- fill CSR ----------
__global__ void fill_pad_k(const void* ei, int E, const int* __restrict__ deg,
                           int* cursor, const int* __restrict__ rowptr,
                           uint2* __restrict__ epad, const int* fmt) {
    int e = blockIdx.x * blockDim.x + threadIdx.x;
    if (e < E) {
        int f = *fmt;
        int r = load_idx(ei, e, f);
        int c = load_idx(ei, E + e, f);
        int pos = atomicAdd(&cursor[c], 1);
        int d = deg[r];
        float v = 1.0f / (float)(d < 1 ? 1 : d);
        epad[pos] = make_uint2((unsigned)r, __float_as_uint(v));
    }
}

__global__ void pad_fill_k(const int* __restrict__ rowptr,
                           const int* __restrict__ cursor,
                           uint2* __restrict__ epad) {
    int c = blockIdx.x * blockDim.x + threadIdx.x;
    if (c >= NNODES) return;
    for (int p = cursor[c]; p < rowptr[c + 1]; ++p)
        epad[p] = make_uint2(0u, 0u);
}

// ---------- X2 = (P^T)^2 via two-level sparse CSR walk; diag k=1,2 fused ------
__global__ __launch_bounds__(256) void x2build_k(
    const int* __restrict__ rowptr, const uint2* __restrict__ epad,
    unsigned char* __restrict__ Y8, float* __restrict__ rw) {
    __shared__ float row[NNODES];
    __shared__ float dia1;
    const int c = blockIdx.x;
    const int t = threadIdx.x;
    for (int i = t; i < NNODES; i += 256) row[i] = 0.f;
    if (t == 0) dia1 = 0.f;
    __syncthreads();
    const int beg = rowptr[c], end = rowptr[c + 1];
    const int g = t >> 4;        // e1 slot [0,16)
    const int l = t & 15;        // e2 lane [0,16)
    for (int i1 = beg + g; i1 < end; i1 += 16) {
        uint2 e1 = epad[i1];
        float v = __uint_as_float(e1.y);
        if (v != 0.f) {
            int r = (int)e1.x;
            if (r == c && l == 0) atomicAdd(&dia1, v);
            int b2 = rowptr[r], n2 = rowptr[r + 1];
            for (int j = b2 + l; j < n2; j += 16) {
                uint2 e2 = epad[j];
                float w = __uint_as_float(e2.y);
                if (w != 0.f) atomicAdd(&row[e2.x], v * w);
            }
        }
    }
    __syncthreads();
    if (t == 0) {
        rw[c * LWALK + 0] = dia1;       // diag k=1 (exact fp32)
        rw[c * LWALK + 1] = row[c];     // diag k=2 (fp32, pre-quantize)
    }
    float f[16];
    const int base = t * 16;
#pragma unroll
    for (int u = 0; u < 16; ++u) f[u] = row[base + u] * FP8_SCALE;
    uint4n o = enc16f(f);
    __builtin_nontemporal_store(o, (uint4n*)(Y8 + (size_t)c * NNODES + base));
}

// ---------- fused fp8 SpMM (+optional pairdiag in appended blocks) ----------
// Round-7 geometry: 8 slabs x 512 cols, slab = bid & 7 -> each XCD owns ONE
// 512-col slab. Per-XCD L2 set: X-slab 2 MB (read x16 reuse) + Y-slab 2 MB
// (written with PLAIN stores, becomes next pass's X-slab on the SAME XCD)
// = 4 MB L2. Gathers should be L2 hits instead of Infinity-Cache service.
__global__ __launch_bounds__(256) void fused8_k(
    const unsigned char* __restrict__ X8, unsigned char* __restrict__ Y8,
    const int* __restrict__ rowptr, const uint2* __restrict__ epad,
    float* __restrict__ rw, int kcol,
    const unsigned char* __restrict__ PA, const unsigned char* __restrict__ PB,
    int colO, int colE, int nspmm) {
    __shared__ __half bt[64][66];
    __shared__ __half ct[64][66];
    const int bid = blockIdx.x;
    if (bid < nspmm) {
        const int slab = bid & 7;                  // XCD-pinned 512-col slab
        const int lane = threadIdx.x & 63;
        const int c =
            __builtin_amdgcn_readfirstlane((bid >> 3) * 4 + (threadIdx.x >> 6));
        const int colo = slab * 512 + lane * 8;    // fp8 byte offset
        const unsigned char* Xs = X8 + colo;
        const int beg = rowptr[c], end = rowptr[c + 1];  // padded %4
        float a[8];
#pragma unroll
        for (int u = 0; u < 8; ++u) a[u] = 0.f;
        for (int e = beg; e < end; e += 4) {
            uint2 ed[4];
#pragma unroll
            for (int j = 0; j < 4; ++j) ed[j] = epad[e + j];
            uint2 x[4];
#pragma unroll
            for (int j = 0; j < 4; ++j)
                x[j] = *(const uint2*)(Xs + (size_t)ed[j].x * NNODES);
#pragma unroll
            for (int j = 0; j < 4; ++j) {
                float v = __uint_as_float(ed[j].y);
                float f[8];
                dec8f(x[j].x, x[j].y, f);
#pragma unroll
                for (int u = 0; u < 8; ++u) a[u] = fmaf(f[u], v, a[u]);
            }
        }
        if ((c >> 9) == slab && lane == ((c & 511) >> 3)) {
            float d = 0.f;
#pragma unroll
            for (int u = 0; u < 8; ++u)
                if ((c & 7) == u) d = a[u];
            rw[c * LWALK + kcol] = d * FP8_INV;
        }
        unsigned int lo, hi;
        enc8f(a, &lo, &hi);
        // PLAIN store (not nontemporal): keep Y-slab resident in this XCD's L2
        *(uint2*)(Y8 + (size_t)c * NNODES + colo) = make_uint2(lo, hi);
    } else {
        const int pb = bid - nspmm;      // 1024 pair blocks
        const int i0 = (pb & 63) * 64;
        const int Jbeg = (pb >> 6) * (NNODES / 16);
        const int Jend = Jbeg + (NNODES / 16);
        const int t = threadIdx.x;
        const int li = t >> 2;
        const int q = t & 3;
        const int c0 = q * 16;
        float accO = 0.f, accE = 0.f;
        for (int J = Jbeg; J < Jend; J += 64) {
            uint4n b16 = __builtin_nontemporal_load(
                (const uint4n*)(PB + (size_t)(J + li) * NNODES + i0 + c0));
            uint4n g16 = __builtin_nontemporal_load(
                (const uint4n*)(PA + (size_t)(J + li) * NNODES + i0 + c0));
            __syncthreads();
            float bf[16], gf[16];
            dec16f(b16, bf);
            dec16f(g16, gf);
#pragma unroll
            for (int s = 0; s < 16; ++s) {
                bt[c0 + s][li] = __float2half(bf[s]);  // fp8 values exact in fp16
                ct[c0 + s][li] = __float2half(gf[s]);
            }
            __syncthreads();
            uint4n a16 = __builtin_nontemporal_load(
                (const uint4n*)(PA + (size_t)(i0 + li) * NNODES + J + c0));
            float af[16];
            dec16f(a16, af);
#pragma unroll
            for (int s = 0; s < 16; ++s) {
                accO = fmaf(af[s], __half2float(bt[li][c0 + s]), accO);
                accE = fmaf(af[s], __half2float(ct[li][c0 + s]), accE);
            }
        }
        accO += __shfl_xor(accO, 1);
        accO += __shfl_xor(accO, 2);
        accE += __shfl_xor(accE, 1);
        accE += __shfl_xor(accE, 2);
        if (q == 0) {
            atomicAdd(&rw[(i0 + li) * LWALK + colO], accO * FP8_INV2);
            atomicAdd(&rw[(i0 + li) * LWALK + colE], accE * FP8_INV2);
        }
    }
}

// ---------- final: pairdiag(X8,X7) for k=15,16 ----------
__global__ __launch_bounds__(256) void finale_k(
    const unsigned char* __restrict__ PA, const unsigned char* __restrict__ PB,
    float* __restrict__ rw, const float* __restrict__ W,
    const float* __restrict__ b, float* __restrict__ out, int npair) {
    __shared__ __half bt[64][66];
    __shared__ __half ct[64][66];
    const int bid = blockIdx.x;
    if (bid < npair) {
        const int pb = bid;
        const int i0 = (pb & 63) * 64;
        const int Jbeg = (pb >> 6) * (NNODES / 16);
        const int Jend = Jbeg + (NNODES / 16);
        const int t = threadIdx.x;
        const int li = t >> 2;
        const int q = t & 3;
        const int c0 = q * 16;
        float accO = 0.f, accE = 0.f;
        for (int J = Jbeg; J < Jend; J += 64) {
            uint4n b16 = __builtin_nontemporal_load(
                (const uint4n*)(PB + (size_t)(J + li) * NNODES + i0 + c0));
            uint4n g16 = __builtin_nontemporal_load(
                (const uint4n*)(PA + (size_t)(J + li) * NNODES + i0 + c0));
            __syncthreads();
            float bf[16], gf[16];
            dec16f(b16, bf);
            dec16f(g16, gf);
#pragma unroll
            for (int s = 0; s < 16; ++s) {
                bt[c0 + s][li] = __float2half(bf[s]);
                ct[c0 + s][li] = __float2half(gf[s]);
            }
            __syncthreads();
            uint4n a16 = __builtin_nontemporal_load(
                (const uint4n*)(PA + (size_t)(i0 + li) * NNODES + J + c0));
            float af[16];
            dec16f(a16, af);
#pragma unroll
            for (int s = 0; s < 16; ++s) {
                accO = fmaf(af[s], __half2float(bt[li][c0 + s]), accO);
                accE = fmaf(af[s], __half2float(ct[li][c0 + s]), accE);
            }
        }
        accO += __shfl_xor(accO, 1);
        accO += __shfl_xor(accO, 2);
        accE += __shfl_xor(accE, 1);
        accE += __shfl_xor(accE, 2);
        if (q == 0) {
            atomicAdd(&rw[(i0 + li) * LWALK + 14], accO * FP8_INV2);
            atomicAdd(&rw[(i0 + li) * LWALK + 15], accE * FP8_INV2);
        }
    }
}

// ---------- final linear (separate; needs all rw complete) ----------
__global__ void linear_k(const float* __restrict__ rw, const float* __restrict__ W,
                         const float* __restrict__ b, float* __restrict__ out) {
    int i = blockIdx.x * blockDim.x + threadIdx.x;
    if (i >= NNODES * ODIM) return;
    int s = i >> 3, d = i & 7;
    float acc = b[d];
#pragma unroll
    for (int k = 0; k < LWALK; ++k)
        acc = fmaf(rw[s * LWALK + k], W[d * LWALK + k], acc);
    out[i] = acc;
}

extern "C" void kernel_launch(void* const* d_in, const int* in_sizes, int n_in,
                              void* d_out, int out_size, void* d_ws, size_t ws_size,
                              hipStream_t stream) {
    const void* ei = d_in[0];
    int E = in_sizes[0] / 2;
    const float* W = (const float*)d_in[2];
    const float* bias = (const float*)d_in[3];
    float* out = (float*)d_out;

    char* ws = (char*)d_ws;
    size_t off = 0;
    auto alloc = [&](size_t bytes) -> char* {
        char* p = ws + off;
        off = (off + bytes + 255) & ~(size_t)255;
        return p;
    };
    int* flag = (int*)alloc(4);
    int* deg = (int*)alloc(NNODES * 4);
    int* cnt = (int*)alloc(NNODES * 4);
    int* rowptr = (int*)alloc((NNODES + 1) * 4);
    int* cursor = (int*)alloc(NNODES * 4);
    uint2* epad = (uint2*)alloc(((size_t)E + 4 * NNODES) * 8);
    float* rw = (float*)alloc(NNODES * LWALK * 4);
    unsigned char* A = (unsigned char*)alloc((size_t)NNODES * NNODES);
    unsigned char* B = (unsigned char*)alloc((size_t)NNODES * NNODES);
    unsigned char* C = (unsigned char*)alloc((size_t)NNODES * NNODES);

    (void)hipMemsetAsync(deg, 0, NNODES * 4, stream);
    (void)hipMemsetAsync(cnt, 0, NNODES * 4, stream);
    (void)hipMemsetAsync(rw, 0, NNODES * LWALK * 4, stream);
    detect_fmt_k<<<1, 64, 0, stream>>>(ei, E, flag);
    build_deg_cnt_k<<<(E + 255) / 256, 256, 0, stream>>>(ei, E, deg, cnt, flag);
    scan_k<<<1, 1024, 0, stream>>>(cnt, rowptr, cursor);
    fill_pad_k<<<(E + 255) / 256, 256, 0, stream>>>(ei, E, deg, cursor, rowptr,
                                                    epad, flag);
    pad_fill_k<<<(NNODES + 255) / 256, 256, 0, stream>>>(rowptr, cursor, epad);

    // X2 (fp8, scaled) directly from the CSR; diags k=1,2 fused.
    x2build_k<<<NNODES, 256, 0, stream>>>(rowptr, epad, A, rw);

    // fp8 chain with fused pairdiags. Rotation: X2=A,X3=B,X4=C,X5=A,X6=B,X7=C,X8=A
    // SG = 8192: 1024 col-groups x 8 XCD-pinned 512-col slabs.
    const int SG = 8192;
    fused8_k<<<SG, 256, 0, stream>>>(A, B, rowptr, epad, rw, 2, nullptr, nullptr, 0, 0, SG);            // X3
    fused8_k<<<SG, 256, 0, stream>>>(B, C, rowptr, epad, rw, 3, nullptr, nullptr, 0, 0, SG);            // X4
    fused8_k<<<SG, 256, 0, stream>>>(C, A, rowptr, epad, rw, 4, nullptr, nullptr, 0, 0, SG);            // X5
    fused8_k<<<SG + 1024, 256, 0, stream>>>(A, B, rowptr, epad, rw, 5, A, C, 8, 9, SG);                 // X6 + k9,10
    fused8_k<<<SG + 1024, 256, 0, stream>>>(B, C, rowptr, epad, rw, 6, B, A, 10, 11, SG);               // X7 + k11,12
    fused8_k<<<SG + 1024, 256, 0, stream>>>(C, A, rowptr, epad, rw, 7, C, B, 12, 13, SG);               // X8 + k13,14
    finale_k<<<1024, 256, 0, stream>>>(A, C, rw, W, bias, out, 1024);                                   // k15,16
    linear_k<<<(NNODES * ODIM + 255) / 256, 256, 0, stream>>>(rw, W, bias, out);
}